// Round 5
// baseline (234.286 us; speedup 1.0000x reference)
//
#include <hip/hip_runtime.h>

typedef unsigned short u16;
typedef unsigned int u32;
typedef unsigned long long u64;
typedef __attribute__((ext_vector_type(4))) float vfloat4;
typedef __attribute__((ext_vector_type(8))) short vshort8;
typedef __attribute__((ext_vector_type(4))) short vshort4;

#define DEV __device__ __forceinline__

DEV u16 f2b(float f){
  u32 u = __builtin_bit_cast(u32, f);
  u = (u + 0x7fffu + ((u >> 16) & 1u)) >> 16;
  return (u16)u;
}
DEV float b2f(u16 h){ u32 u = ((u32)h) << 16; return __builtin_bit_cast(float, u); }

typedef __attribute__((address_space(3))) u32 as3u;
typedef __attribute__((address_space(1))) u32 as1u;
DEV void gll16(const u16* g, const u16* l){
  __builtin_amdgcn_global_load_lds((const as1u*)(u64)(uintptr_t)g,
                                   (as3u*)(u32)(u64)(uintptr_t)l, 16, 0, 0);
}

// ---------------- K1: per-(b,c) sum & sumsq over N=1024 ----------------
__global__ void k_stats(const float* __restrict__ x, float* __restrict__ osum, float* __restrict__ osq){
  int row = blockIdx.x;
  const vfloat4* xr = (const vfloat4*)(x + (size_t)row * 1024);
  vfloat4 v = xr[threadIdx.x];
  float s = v[0]+v[1]+v[2]+v[3];
  float q = v[0]*v[0]+v[1]*v[1]+v[2]*v[2]+v[3]*v[3];
  #pragma unroll
  for (int m = 1; m < 64; m <<= 1){ s += __shfl_xor(s, m); q += __shfl_xor(q, m); }
  __shared__ float ls[4], lq[4];
  int w = threadIdx.x >> 6;
  if ((threadIdx.x & 63) == 0){ ls[w] = s; lq[w] = q; }
  __syncthreads();
  if (threadIdx.x == 0){
    osum[row] = ls[0]+ls[1]+ls[2]+ls[3];
    osq[row]  = lq[0]+lq[1]+lq[2]+lq[3];
  }
}

// ---------------- K2: per-batch GN affine + SE gate ----------------
__global__ void k_prep(const float* __restrict__ sum, const float* __restrict__ sq,
                       const float* __restrict__ gamma, const float* __restrict__ beta,
                       const float* __restrict__ w_se1, const float* __restrict__ b_se1,
                       const float* __restrict__ w_se2, const float* __restrict__ b_se2,
                       float* __restrict__ a_scale, float* __restrict__ bsh, float* __restrict__ gate){
  int b = blockIdx.x, c = threadIdx.x;
  __shared__ float ssh[256], qsh[256], pooled[256], h1[64], meang[32], rstdg[32];
  float s = sum[b*256 + c], q = sq[b*256 + c];
  ssh[c] = s; qsh[c] = q; pooled[c] = s * (1.f/1024.f);
  __syncthreads();
  if (c < 32){
    float gs = 0.f, gq = 0.f;
    #pragma unroll
    for (int i = 0; i < 8; i++){ gs += ssh[c*8+i]; gq += qsh[c*8+i]; }
    float mean = gs * (1.f/8192.f);
    float var  = gq * (1.f/8192.f) - mean*mean;
    meang[c] = mean; rstdg[c] = rsqrtf(var + 1e-5f);
  }
  __syncthreads();
  float rs = rstdg[c>>3], mn = meang[c>>3], g = gamma[c];
  a_scale[b*256+c] = rs*g;
  bsh[b*256+c]     = beta[c] - mn*rs*g;
  if (c < 64){
    float acc = b_se1[c];
    const float* wr = w_se1 + c*256;
    for (int i = 0; i < 256; i++) acc += pooled[i]*wr[i];
    h1[c] = fmaxf(acc, 0.f);
  }
  __syncthreads();
  float acc = b_se2[c];
  const float* wr2 = w_se2 + c*64;
  #pragma unroll
  for (int j = 0; j < 64; j++) acc += h1[j]*wr2[j];
  gate[b*256+c] = 1.f / (1.f + __expf(-acc));
}

// ---------------- K3w: weights -> bf16 ----------------
__global__ void k_wcvt(const float* __restrict__ wq, const float* __restrict__ wp,
                       u16* __restrict__ wqb, u16* __restrict__ wpb){
  int i = blockIdx.x*256 + threadIdx.x;
  if (i < 196608) wqb[i] = f2b(wq[i]);
  else            wpb[i-196608] = f2b(wp[i-196608]);
}

// ---------------- K3: xs_t[b,n,c] = bf16(a*x + bsh), transposed ----------------
__global__ void k_xt(const float* __restrict__ x, const float* __restrict__ a_s,
                     const float* __restrict__ bsh, u16* __restrict__ xs_t){
  __shared__ float t[64][65];
  int b = blockIdx.z, c0 = blockIdx.y*64, n0 = blockIdx.x*64;
  int tid = threadIdx.x;
  int rr = tid >> 4, cc = (tid & 15)*4;
  #pragma unroll
  for (int itr = 0; itr < 4; itr++){
    int r = rr + itr*16;
    int c = c0 + r;
    float a = a_s[b*256 + c], bs = bsh[b*256 + c];
    vfloat4 v = *(const vfloat4*)(x + ((size_t)(b*256 + c))*1024 + n0 + cc);
    t[r][cc]   = v[0]*a + bs;
    t[r][cc+1] = v[1]*a + bs;
    t[r][cc+2] = v[2]*a + bs;
    t[r][cc+3] = v[3]*a + bs;
  }
  __syncthreads();
  int cl = tid & 63, rg = tid >> 6;
  #pragma unroll
  for (int it2 = 0; it2 < 16; it2++){
    int nl = rg*16 + it2;
    xs_t[((size_t)b*1024 + n0 + nl)*256 + c0 + cl] = f2b(t[cl][nl]);
  }
}

// ---------------- K4: qkv GEMM; q[b,n,c] (scale*log2e folded),
//                  K and V as pre-swizzled per-32-j-tile 16KB images ----------
__global__ __launch_bounds__(256) void k_qkv(
    const u16* __restrict__ wq_b, const u16* __restrict__ xs_t,
    const float* __restrict__ b_qkv,
    u16* __restrict__ qt, u16* __restrict__ kph, u16* __restrict__ vph){
  __shared__ u16 Alds[128*40];
  __shared__ u16 Blds[128*40];
  int bid = blockIdx.x;                 // 1536 linear, XCD-aware decode
  int xcd = bid & 7, idx = bid >> 3;
  int b   = xcd*4 + idx/48;
  int rem = idx % 48;
  int o0 = (rem >> 3) * 128;
  int n0 = (rem & 7) * 128;
  int tid = threadIdx.x;
  int w = tid >> 6, lane = tid & 63, lo = lane & 15, hi = lane >> 4;
  int wr = w >> 1, wc = w & 1;
  vfloat4 acc[4][4];
  #pragma unroll
  for (int i = 0; i < 4; i++)
    #pragma unroll
    for (int j = 0; j < 4; j++) acc[i][j] = vfloat4{0.f,0.f,0.f,0.f};

  for (int ks = 0; ks < 8; ks++){
    int c0 = ks*32;
    __syncthreads();
    #pragma unroll
    for (int i = 0; i < 2; i++){
      int cid = tid + i*256;
      int row = cid >> 2, h4 = cid & 3;
      vshort8 a = *(const vshort8*)(wq_b + (o0+row)*256 + c0 + h4*8);
      *(vshort8*)(Alds + row*40 + h4*8) = a;
      vshort8 bl = *(const vshort8*)(xs_t + ((size_t)b*1024 + n0 + row)*256 + c0 + h4*8);
      *(vshort8*)(Blds + row*40 + h4*8) = bl;
    }
    __syncthreads();
    vshort8 af[4], bf[4];
    #pragma unroll
    for (int of = 0; of < 4; of++) af[of] = *(const vshort8*)(Alds + (wr*64+of*16+lo)*40 + hi*8);
    #pragma unroll
    for (int nf = 0; nf < 4; nf++) bf[nf] = *(const vshort8*)(Blds + (wc*64+nf*16+lo)*40 + hi*8);
    #pragma unroll
    for (int of = 0; of < 4; of++)
      #pragma unroll
      for (int nf = 0; nf < 4; nf++)
        acc[of][nf] = __builtin_amdgcn_mfma_f32_16x16x32_bf16(af[of], bf[nf], acc[of][nf], 0, 0, 0);
  }

  int kind = o0 >> 8;                   // 0=q, 1=k, 2=v
  #pragma unroll
  for (int of = 0; of < 4; of++){
    int ob = o0 + wr*64 + of*16 + hi*4;
    vfloat4 bq = *(const vfloat4*)(b_qkv + ob);
    #pragma unroll
    for (int nf = 0; nf < 4; nf++){
      int n = n0 + wc*64 + nf*16 + lo;
      int tile = n >> 5, j = n & 31;
      vfloat4 val = acc[of][nf];
      #pragma unroll
      for (int r = 0; r < 4; r++) val[r] += bq[r];
      if (kind == 0){
        vshort4 p;                      // fold 1/sqrt(C) * log2(e)
        #pragma unroll
        for (int r = 0; r < 4; r++) p[r] = (short)f2b(val[r] * 0.09016844f);
        *(vshort4*)(qt + ((size_t)b*1024 + n)*256 + ob) = p;
      } else if (kind == 1){
        vshort4 p;
        #pragma unroll
        for (int r = 0; r < 4; r++) p[r] = (short)f2b(val[r]);
        int cx = (ob - 256) ^ ((j & 7) << 3);   // XOR-swizzled c within 512B row
        *(vshort4*)(kph + ((size_t)b << 18) + tile*8192 + j*256 + cx) = p;
      } else {
        int pos = ((j >> 2) & 3)*8 + ((j >> 4) << 2) + (j & 3);  // b128-frag order
        #pragma unroll
        for (int r = 0; r < 4; r++){
          int c = ob - 512 + r;
          int off = ((c >> 1) << 6) + (((((c & 1) << 5) + pos)) ^ (((c >> 1) & 7) << 3));
          vph[((size_t)b << 18) + tile*8192 + off] = f2b(val[r]);
        }
      }
    }
  }
}

// ---------------- K5: flash attention + proj + SE gate + residual ----------------
// 512 blocks x 4 waves (2 blocks/CU): i-tile 64 (2 row-waves, f=2), split-j 2
// groups. K LDS dbuf via gll16 + counted vmcnt across raw barriers (never
// drain); V in per-wave register dbuf loaded directly from coalesced image.
__global__ __launch_bounds__(256, 2) void k_attn(
    const u16* __restrict__ qt, const u16* __restrict__ kph, const u16* __restrict__ vph,
    const u16* __restrict__ wp_b, const float* __restrict__ b_proj,
    const float* __restrict__ gate, const float* __restrict__ x,
    float* __restrict__ out){
  __shared__ u16 smem[32768];           // 64KB: K[grp][buf][8192]; epilogue Ox[64][264]
  __shared__ float Ml[4][2][16], Ll[4][2][16];
  int bid = blockIdx.x;                 // 512 blocks
  int xcd = bid & 7, idx = bid >> 3;    // idx 0..63
  int b = xcd*4 + (idx >> 4);
  int i0 = (idx & 15) * 64;
  int tid = threadIdx.x, w = tid >> 6, lane = tid & 63, lo = lane & 15, hi = lane >> 4;
  int g = w >> 1, r = w & 1;

  // Q fragments (scale*log2e folded)
  vshort8 qf[2][8];
  #pragma unroll
  for (int f = 0; f < 2; f++){
    int iq = i0 + r*32 + f*16 + lo;
    #pragma unroll
    for (int ct = 0; ct < 8; ct++)
      qf[f][ct] = *(const vshort8*)(qt + ((size_t)b*1024 + iq)*256 + ct*32 + hi*8);
  }

  vfloat4 Oacc[16][2];
  #pragma unroll
  for (int i = 0; i < 16; i++){ Oacc[i][0] = vfloat4{0.f,0.f,0.f,0.f}; Oacc[i][1] = vfloat4{0.f,0.f,0.f,0.f}; }
  float m_run[2] = {-1e30f, -1e30f}, l_run[2] = {0.f, 0.f};

  int kswz = (lo & 7) << 3;
  int koff[8];
  #pragma unroll
  for (int ct = 0; ct < 8; ct++) koff[ct] = (ct*32 + hi*8) ^ kswz;
  int vbase = (lo >> 1)*64 + ((((lo & 1) << 5) + hi*8) ^ (((lo >> 1) & 7) << 3));

  const u16* kbat = kph + ((size_t)b << 18);
  const u16* vbat = vph + ((size_t)b << 18);

  // stage K tiles {2*rd2, 2*rd2+1} into buf: 2048 16B chunks / 256 thr = 8 each
  auto STAGE = [&](int rd2, int buf){
    int t0 = 2*rd2;
    #pragma unroll
    for (int s = 0; s < 8; s++){
      int cid = s*256 + tid;
      int half = cid >> 10;
      int ch = (cid & 1023) * 8;
      gll16(kbat + (size_t)(t0 + half)*8192 + ch, smem + (half*2 + buf)*8192 + ch);
    }
  };

  vshort8 vA[8], vB[8];
  STAGE(0, 0);
  __builtin_amdgcn_sched_barrier(0);    // pin gll16 issue before V loads
  {
    const u16* vt = vbat + (size_t)g * 8192;
    #pragma unroll
    for (int f8 = 0; f8 < 8; f8++) vA[f8] = *(const vshort8*)(vt + f8*512 + vbase);
    #pragma unroll
    for (int f8 = 0; f8 < 8; f8++) vB[f8] = *(const vshort8*)(vt + (f8+8)*512 + vbase);
  }
  asm volatile("s_waitcnt vmcnt(16)" ::: "memory");   // retire the 8 gll16 only
  __builtin_amdgcn_s_barrier();
  __builtin_amdgcn_sched_barrier(0);

  for (int rd = 0; rd < 16; rd++){
    int buf = rd & 1;
    if (rd < 15) STAGE(rd + 1, buf ^ 1);
    __builtin_amdgcn_sched_barrier(0);  // keep gll16 ahead of everything else
    const u16* Kb = smem + (g*2 + buf)*8192;

    // S^T = K · Q
    vfloat4 st[2][2];
    st[0][0] = vfloat4{0.f,0.f,0.f,0.f}; st[0][1] = vfloat4{0.f,0.f,0.f,0.f};
    st[1][0] = vfloat4{0.f,0.f,0.f,0.f}; st[1][1] = vfloat4{0.f,0.f,0.f,0.f};
    __builtin_amdgcn_s_setprio(1);
    #pragma unroll
    for (int ct = 0; ct < 8; ct++){
      vshort8 k0 = *(const vshort8*)(Kb + lo*256 + koff[ct]);
      vshort8 k1 = *(const vshort8*)(Kb + (16 + lo)*256 + koff[ct]);
      st[0][0] = __builtin_amdgcn_mfma_f32_16x16x32_bf16(k0, qf[0][ct], st[0][0], 0,0,0);
      st[0][1] = __builtin_amdgcn_mfma_f32_16x16x32_bf16(k0, qf[1][ct], st[0][1], 0,0,0);
      st[1][0] = __builtin_amdgcn_mfma_f32_16x16x32_bf16(k1, qf[0][ct], st[1][0], 0,0,0);
      st[1][1] = __builtin_amdgcn_mfma_f32_16x16x32_bf16(k1, qf[1][ct], st[1][1], 0,0,0);
    }
    __builtin_amdgcn_s_setprio(0);

    // online softmax (log2 domain), defer-max THR=8
    float pm[2];
    #pragma unroll
    for (int f = 0; f < 2; f++){
      float a = fmaxf(fmaxf(st[0][f][0], st[0][f][1]), fmaxf(st[0][f][2], st[0][f][3]));
      float c = fmaxf(fmaxf(st[1][f][0], st[1][f][1]), fmaxf(st[1][f][2], st[1][f][3]));
      float p = fmaxf(a, c);
      p = fmaxf(p, __shfl_xor(p, 16));
      p = fmaxf(p, __shfl_xor(p, 32));
      pm[f] = p;
    }
    bool okd = (pm[0] - m_run[0] <= 8.f) && (pm[1] - m_run[1] <= 8.f);
    if (!__all(okd)){
      #pragma unroll
      for (int f = 0; f < 2; f++){
        float mn = fmaxf(m_run[f], pm[f]);
        float corr = exp2f(m_run[f] - mn);
        #pragma unroll
        for (int i = 0; i < 16; i++) Oacc[i][f] *= corr;
        l_run[f] *= corr;
        m_run[f] = mn;
      }
    }
    vshort8 pf[2];
    #pragma unroll
    for (int f = 0; f < 2; f++){
      float p[8], ps = 0.f;
      #pragma unroll
      for (int e = 0; e < 4; e++){
        p[e]   = exp2f(st[0][f][e] - m_run[f]);
        p[4+e] = exp2f(st[1][f][e] - m_run[f]);
        ps += p[e] + p[4+e];
      }
      ps += __shfl_xor(ps, 16); ps += __shfl_xor(ps, 32);
      l_run[f] += ps;
      #pragma unroll
      for (int e2 = 0; e2 < 8; e2++) pf[f][e2] = (short)f2b(p[e2]);
    }

    // PV from registers; refill V dbuf for next tile right after consumption
    const u16* vt = vbat + (size_t)(2*(rd+1) + g)*8192;
    __builtin_amdgcn_s_setprio(1);
    #pragma unroll
    for (int c8 = 0; c8 < 8; c8++){
      Oacc[c8][0] = __builtin_amdgcn_mfma_f32_16x16x32_bf16(vA[c8], pf[0], Oacc[c8][0], 0,0,0);
      Oacc[c8][1] = __builtin_amdgcn_mfma_f32_16x16x32_bf16(vA[c8], pf[1], Oacc[c8][1], 0,0,0);
    }
    __builtin_amdgcn_s_setprio(0);
    if (rd < 15){
      #pragma unroll
      for (int f8 = 0; f8 < 8; f8++) vA[f8] = *(const vshort8*)(vt + f8*512 + vbase);
    }
    __builtin_amdgcn_s_setprio(1);
    #pragma unroll
    for (int c8 = 0; c8 < 8; c8++){
      Oacc[c8+8][0] = __builtin_amdgcn_mfma_f32_16x16x32_bf16(vB[c8], pf[0], Oacc[c8+8][0], 0,0,0);
      Oacc[c8+8][1] = __builtin_amdgcn_mfma_f32_16x16x32_bf16(vB[c8], pf[1], Oacc[c8+8][1], 0,0,0);
    }
    __builtin_amdgcn_s_setprio(0);
    if (rd < 15){
      #pragma unroll
      for (int f8 = 0; f8 < 8; f8++) vB[f8] = *(const vshort8*)(vt + (f8+8)*512 + vbase);
    }

    // retire this iter's 8 gll16 (keep 16 V loads in flight), then barrier
    asm volatile("s_waitcnt vmcnt(16)" ::: "memory");
    __builtin_amdgcn_s_barrier();
    __builtin_amdgcn_sched_barrier(0);
  }

  __syncthreads();                      // full drain before LDS reuse

  // -------- merge split-j partners (w <-> w^2) --------
  if (hi == 0){ Ml[w][0][lo] = m_run[0]; Ml[w][1][lo] = m_run[1]; }
  __syncthreads();
  int pw = w ^ 2;
  #pragma unroll
  for (int f = 0; f < 2; f++){
    float mp = Ml[pw][f][lo];
    float mm = fmaxf(m_run[f], mp);
    float sc = exp2f(m_run[f] - mm);
    l_run[f] *= sc;
    #pragma unroll
    for (int i = 0; i < 16; i++) Oacc[i][f] *= sc;
  }
  if (hi == 0){ Ll[w][0][lo] = l_run[0]; Ll[w][1][lo] = l_run[1]; }
  __syncthreads();

  u16* Ox = smem;                       // [64][264] bf16, +8 pad
  if (g == 1){                          // write partial (pre-normalized) bf16
    #pragma unroll
    for (int f = 0; f < 2; f++){
      int irow = r*32 + f*16 + lo;
      #pragma unroll
      for (int i = 0; i < 16; i++){
        vshort4 p;
        #pragma unroll
        for (int e = 0; e < 4; e++) p[e] = (short)f2b(Oacc[i][f][e]);
        *(vshort4*)(Ox + irow*264 + i*16 + hi*4) = p;
      }
    }
  }
  __syncthreads();
  if (g == 0){                          // add partner partial, normalize, write back
    #pragma unroll
    for (int f = 0; f < 2; f++){
      float lsum = l_run[f] + Ll[pw][f][lo];
      float inv = 1.f / lsum;
      int irow = r*32 + f*16 + lo;
      #pragma unroll
      for (int i = 0; i < 16; i++){
        vshort4 pp = *(const vshort4*)(Ox + irow*264 + i*16 + hi*4);
        vshort4 po;
        #pragma unroll
        for (int e = 0; e < 4; e++) po[e] = (short)f2b((Oacc[i][f][e] + b2f((u16)pp[e])) * inv);
        *(vshort4*)(Ox + irow*264 + i*16 + hi*4) = po;
      }
    }
  }
  __syncthreads();

  // -------- proj + SE gate + residual (4 waves; wave w: o in [w*64, w*64+64)) ----
  vfloat4 acc2[4][4];
  #pragma unroll
  for (int i = 0; i < 4; i++)
    #pragma unroll
    for (int j = 0; j < 4; j++) acc2[i][j] = vfloat4{0.f,0.f,0.f,0.f};
  #pragma unroll
  for (int ct = 0; ct < 8; ct++){
    vshort8 wf[4], ofr[4];
    #pragma unroll
    for (int o4 = 0; o4 < 4; o4++)
      wf[o4] = *(const vshort8*)(wp_b + (w*64 + o4*16 + lo)*256 + ct*32 + hi*8);
    #pragma unroll
    for (int i4 = 0; i4 < 4; i4++)
      ofr[i4] = *(const vshort8*)(Ox + (i4*16 + lo)*264 + ct*32 + hi*8);
    #pragma unroll
    for (int o4 = 0; o4 < 4; o4++)
      #pragma unroll
      for (int i4 = 0; i4 < 4; i4++)
        acc2[o4][i4] = __builtin_amdgcn_mfma_f32_16x16x32_bf16(wf[o4], ofr[i4], acc2[o4][i4], 0,0,0);
  }

  #pragma unroll
  for (int o4 = 0; o4 < 4; o4++){
    int ob = w*64 + o4*16 + hi*4;
    vfloat4 bp = *(const vfloat4*)(b_proj + ob);
    vfloat4 gt = *(const vfloat4*)(gate + b*256 + ob);
    #pragma unroll
    for (int i4 = 0; i4 < 4; i4++){
      int n = i0 + i4*16 + lo;
      #pragma unroll
      for (int e = 0; e < 4; e++){
        size_t idxo = ((size_t)(b*256) + ob + e)*1024 + n;
        out[idxo] = x[idxo] + (acc2[o4][i4][e] + bp[e]) * gt[e];
      }
    }
  }
}

// ---------------- launch ----------------
extern "C" void kernel_launch(void* const* d_in, const int* in_sizes, int n_in,
                              void* d_out, int out_size, void* d_ws, size_t ws_size,
                              hipStream_t stream){
  const float* x      = (const float*)d_in[0];
  const float* gamma  = (const float*)d_in[1];
  const float* beta   = (const float*)d_in[2];
  const float* w_qkv  = (const float*)d_in[3];
  const float* b_qkv  = (const float*)d_in[4];
  const float* w_proj = (const float*)d_in[5];
  const float* b_proj = (const float*)d_in[6];
  const float* w_se1  = (const float*)d_in[7];
  const float* b_se1  = (const float*)d_in[8];
  const float* w_se2  = (const float*)d_in[9];
  const float* b_se2  = (const float*)d_in[10];
  float* out = (float*)d_out;
  char* ws = (char*)d_ws;

  float* sum  = (float*)(ws + 0);          // 32 KB
  float* sq   = (float*)(ws + 32768);      // 32 KB
  float* a_s  = (float*)(ws + 65536);      // 32 KB
  float* bsh  = (float*)(ws + 98304);      // 32 KB
  float* gate = (float*)(ws + 131072);     // 32 KB
  u16* wq_b   = (u16*)(ws + 163840);       // 384 KB
  u16* wp_b   = (u16*)(ws + 557056);       // 128 KB
  u16* xs_t   = (u16*)(ws + 688128);       // 16 MB  [B,N,C] bf16
  u16* qt     = (u16*)(ws + 17465344);     // 16 MB  [B,N,C] bf16 (scale*log2e folded)
  u16* kph    = (u16*)(ws + 34242560);     // 16 MB  K tile images [B][32][8192]
  u16* vph    = (u16*)(ws + 51019776);     // 16 MB  V tile images [B][32][8192]

  k_stats<<<8192, 256, 0, stream>>>(x, sum, sq);
  k_wcvt <<<1024, 256, 0, stream>>>(w_qkv, w_proj, wq_b, wp_b);
  k_prep <<<32,   256, 0, stream>>>(sum, sq, gamma, beta, w_se1, b_se1, w_se2, b_se2, a_s, bsh, gate);
  k_xt   <<<dim3(16,4,32), 256, 0, stream>>>(x, a_s, bsh, xs_t);
  k_qkv  <<<1536, 256, 0, stream>>>(wq_b, xs_t, b_qkv, qt, kph, vph);
  k_attn <<<512,  256, 0, stream>>>(qt, kph, vph, wp_b, b_proj, gate, x, out);
}

// Round 6
// 140.238 us; speedup vs baseline: 1.6706x; 1.6706x over previous
//
#include <hip/hip_runtime.h>

typedef unsigned short u16;
typedef unsigned int u32;
typedef unsigned long long u64;
typedef __attribute__((ext_vector_type(4))) float vfloat4;
typedef __attribute__((ext_vector_type(8))) short vshort8;
typedef __attribute__((ext_vector_type(4))) short vshort4;

#define DEV __device__ __forceinline__

DEV u16 f2b(float f){
  u32 u = __builtin_bit_cast(u32, f);
  u = (u + 0x7fffu + ((u >> 16) & 1u)) >> 16;
  return (u16)u;
}

typedef __attribute__((address_space(3))) u32 as3u;
typedef __attribute__((address_space(1))) u32 as1u;
DEV void gll16(const u16* g, const u16* l){
  __builtin_amdgcn_global_load_lds((const as1u*)(u64)(uintptr_t)g,
                                   (as3u*)(u32)(u64)(uintptr_t)l, 16, 0, 0);
}

// ---------------- K1: per-(b,c) sum & sumsq over N=1024 ----------------
__global__ void k_stats(const float* __restrict__ x, float* __restrict__ osum, float* __restrict__ osq){
  int row = blockIdx.x;
  const vfloat4* xr = (const vfloat4*)(x + (size_t)row * 1024);
  vfloat4 v = xr[threadIdx.x];
  float s = v[0]+v[1]+v[2]+v[3];
  float q = v[0]*v[0]+v[1]*v[1]+v[2]*v[2]+v[3]*v[3];
  #pragma unroll
  for (int m = 1; m < 64; m <<= 1){ s += __shfl_xor(s, m); q += __shfl_xor(q, m); }
  __shared__ float ls[4], lq[4];
  int w = threadIdx.x >> 6;
  if ((threadIdx.x & 63) == 0){ ls[w] = s; lq[w] = q; }
  __syncthreads();
  if (threadIdx.x == 0){
    osum[row] = ls[0]+ls[1]+ls[2]+ls[3];
    osq[row]  = lq[0]+lq[1]+lq[2]+lq[3];
  }
}

// ---------------- K2: per-batch GN affine + SE gate ----------------
__global__ void k_prep(const float* __restrict__ sum, const float* __restrict__ sq,
                       const float* __restrict__ gamma, const float* __restrict__ beta,
                       const float* __restrict__ w_se1, const float* __restrict__ b_se1,
                       const float* __restrict__ w_se2, const float* __restrict__ b_se2,
                       float* __restrict__ a_scale, float* __restrict__ bsh, float* __restrict__ gate){
  int b = blockIdx.x, c = threadIdx.x;
  __shared__ float ssh[256], qsh[256], pooled[256], h1[64], meang[32], rstdg[32];
  float s = sum[b*256 + c], q = sq[b*256 + c];
  ssh[c] = s; qsh[c] = q; pooled[c] = s * (1.f/1024.f);
  __syncthreads();
  if (c < 32){
    float gs = 0.f, gq = 0.f;
    #pragma unroll
    for (int i = 0; i < 8; i++){ gs += ssh[c*8+i]; gq += qsh[c*8+i]; }
    float mean = gs * (1.f/8192.f);
    float var  = gq * (1.f/8192.f) - mean*mean;
    meang[c] = mean; rstdg[c] = rsqrtf(var + 1e-5f);
  }
  __syncthreads();
  float rs = rstdg[c>>3], mn = meang[c>>3], g = gamma[c];
  a_scale[b*256+c] = rs*g;
  bsh[b*256+c]     = beta[c] - mn*rs*g;
  if (c < 64){
    float acc = b_se1[c];
    const float* wr = w_se1 + c*256;
    for (int i = 0; i < 256; i++) acc += pooled[i]*wr[i];
    h1[c] = fmaxf(acc, 0.f);
  }
  __syncthreads();
  float acc = b_se2[c];
  const float* wr2 = w_se2 + c*64;
  #pragma unroll
  for (int j = 0; j < 64; j++) acc += h1[j]*wr2[j];
  gate[b*256+c] = 1.f / (1.f + __expf(-acc));
}

// ---------------- K3w: weights -> bf16 ----------------
__global__ void k_wcvt(const float* __restrict__ wq, const float* __restrict__ wp,
                       u16* __restrict__ wqb, u16* __restrict__ wpb){
  int i = blockIdx.x*256 + threadIdx.x;
  if (i < 196608) wqb[i] = f2b(wq[i]);
  else            wpb[i-196608] = f2b(wp[i-196608]);
}

// ---------------- K3: xs_t[b,n,c] = bf16(a*x + bsh), transposed ----------------
__global__ void k_xt(const float* __restrict__ x, const float* __restrict__ a_s,
                     const float* __restrict__ bsh, u16* __restrict__ xs_t){
  __shared__ float t[64][65];
  int b = blockIdx.z, c0 = blockIdx.y*64, n0 = blockIdx.x*64;
  int tid = threadIdx.x;
  int rr = tid >> 4, cc = (tid & 15)*4;
  #pragma unroll
  for (int itr = 0; itr < 4; itr++){
    int r = rr + itr*16;
    int c = c0 + r;
    float a = a_s[b*256 + c], bs = bsh[b*256 + c];
    vfloat4 v = *(const vfloat4*)(x + ((size_t)(b*256 + c))*1024 + n0 + cc);
    t[r][cc]   = v[0]*a + bs;
    t[r][cc+1] = v[1]*a + bs;
    t[r][cc+2] = v[2]*a + bs;
    t[r][cc+3] = v[3]*a + bs;
  }
  __syncthreads();
  int cl = tid & 63, rg = tid >> 6;
  #pragma unroll
  for (int it2 = 0; it2 < 16; it2++){
    int nl = rg*16 + it2;
    xs_t[((size_t)b*1024 + n0 + nl)*256 + c0 + cl] = f2b(t[cl][nl]);
  }
}

// ---------------- K4: qkv GEMM; q[b,n,c] (scale*log2e folded),
//                  K and V as pre-swizzled per-32-j-tile 16KB images ----------
__global__ __launch_bounds__(256) void k_qkv(
    const u16* __restrict__ wq_b, const u16* __restrict__ xs_t,
    const float* __restrict__ b_qkv,
    u16* __restrict__ qt, u16* __restrict__ kph, u16* __restrict__ vph){
  __shared__ u16 Alds[128*40];
  __shared__ u16 Blds[128*40];
  int bid = blockIdx.x;                 // 1536 linear, XCD-aware decode
  int xcd = bid & 7, idx = bid >> 3;
  int b   = xcd*4 + idx/48;
  int rem = idx % 48;
  int o0 = (rem >> 3) * 128;
  int n0 = (rem & 7) * 128;
  int tid = threadIdx.x;
  int w = tid >> 6, lane = tid & 63, lo = lane & 15, hi = lane >> 4;
  int wr = w >> 1, wc = w & 1;
  vfloat4 acc[4][4];
  #pragma unroll
  for (int i = 0; i < 4; i++)
    #pragma unroll
    for (int j = 0; j < 4; j++) acc[i][j] = vfloat4{0.f,0.f,0.f,0.f};

  for (int ks = 0; ks < 8; ks++){
    int c0 = ks*32;
    __syncthreads();
    #pragma unroll
    for (int i = 0; i < 2; i++){
      int cid = tid + i*256;
      int row = cid >> 2, h4 = cid & 3;
      vshort8 a = *(const vshort8*)(wq_b + (o0+row)*256 + c0 + h4*8);
      *(vshort8*)(Alds + row*40 + h4*8) = a;
      vshort8 bl = *(const vshort8*)(xs_t + ((size_t)b*1024 + n0 + row)*256 + c0 + h4*8);
      *(vshort8*)(Blds + row*40 + h4*8) = bl;
    }
    __syncthreads();
    vshort8 af[4], bf[4];
    #pragma unroll
    for (int of = 0; of < 4; of++) af[of] = *(const vshort8*)(Alds + (wr*64+of*16+lo)*40 + hi*8);
    #pragma unroll
    for (int nf = 0; nf < 4; nf++) bf[nf] = *(const vshort8*)(Blds + (wc*64+nf*16+lo)*40 + hi*8);
    #pragma unroll
    for (int of = 0; of < 4; of++)
      #pragma unroll
      for (int nf = 0; nf < 4; nf++)
        acc[of][nf] = __builtin_amdgcn_mfma_f32_16x16x32_bf16(af[of], bf[nf], acc[of][nf], 0, 0, 0);
  }

  int kind = o0 >> 8;                   // 0=q, 1=k, 2=v
  #pragma unroll
  for (int of = 0; of < 4; of++){
    int ob = o0 + wr*64 + of*16 + hi*4;
    vfloat4 bq = *(const vfloat4*)(b_qkv + ob);
    #pragma unroll
    for (int nf = 0; nf < 4; nf++){
      int n = n0 + wc*64 + nf*16 + lo;
      int tile = n >> 5, j = n & 31;
      vfloat4 val = acc[of][nf];
      #pragma unroll
      for (int r = 0; r < 4; r++) val[r] += bq[r];
      if (kind == 0){
        vshort4 p;                      // fold 1/sqrt(C) * log2(e)
        #pragma unroll
        for (int r = 0; r < 4; r++) p[r] = (short)f2b(val[r] * 0.09016844f);
        *(vshort4*)(qt + ((size_t)b*1024 + n)*256 + ob) = p;
      } else if (kind == 1){
        vshort4 p;
        #pragma unroll
        for (int r = 0; r < 4; r++) p[r] = (short)f2b(val[r]);
        int cx = (ob - 256) ^ ((j & 7) << 3);   // XOR-swizzled c within 512B row
        *(vshort4*)(kph + ((size_t)b << 18) + tile*8192 + j*256 + cx) = p;
      } else {
        int pos = ((j >> 2) & 3)*8 + ((j >> 4) << 2) + (j & 3);  // b128-frag order
        #pragma unroll
        for (int r = 0; r < 4; r++){
          int c = ob - 512 + r;
          int off = ((c >> 1) << 6) + (((((c & 1) << 5) + pos)) ^ (((c >> 1) & 7) << 3));
          vph[((size_t)b << 18) + tile*8192 + off] = f2b(val[r]);
        }
      }
    }
  }
}

// ---------------- K5: flash attention + proj + SE gate + residual ----------------
// R2 dataflow (i-tile 128, 4 row-waves, f=2, K+V staged from images) with a
// depth-2 staging pipeline: TRIPLE-buffered slots, one raw s_barrier + one
// counted s_waitcnt vmcnt(8) per iter (never drains in main loop). XCD-pinned.
__global__ __launch_bounds__(256, 1) void k_attn(
    const u16* __restrict__ qt, const u16* __restrict__ kph, const u16* __restrict__ vph,
    const u16* __restrict__ wp_b, const float* __restrict__ b_proj,
    const float* __restrict__ gate, const float* __restrict__ x,
    float* __restrict__ out){
  __shared__ u16 smem[49152];           // 96KB: K slots [3][8192] | V slots at +24576
  int bid = blockIdx.x;                 // 256 blocks, XCD-pinned
  int xcd = bid & 7, idx = bid >> 3;    // idx 0..31
  int b = xcd*4 + (idx >> 3);
  int i0 = (idx & 7) * 128;
  int tid = threadIdx.x, w = tid >> 6, lane = tid & 63, lo = lane & 15, hi = lane >> 4;

  // Q fragments (scale*log2e folded)
  vshort8 qf[2][8];
  #pragma unroll
  for (int f = 0; f < 2; f++){
    int iq = i0 + w*32 + f*16 + lo;
    #pragma unroll
    for (int ct = 0; ct < 8; ct++)
      qf[f][ct] = *(const vshort8*)(qt + ((size_t)b*1024 + iq)*256 + ct*32 + hi*8);
  }

  vfloat4 Oacc[16][2];
  #pragma unroll
  for (int i = 0; i < 16; i++){ Oacc[i][0] = vfloat4{0.f,0.f,0.f,0.f}; Oacc[i][1] = vfloat4{0.f,0.f,0.f,0.f}; }
  float m_run[2] = {-1e30f, -1e30f}, l_run[2] = {0.f, 0.f};

  int kswz = (lo & 7) << 3;
  int koff[8];
  #pragma unroll
  for (int ct = 0; ct < 8; ct++) koff[ct] = (ct*32 + hi*8) ^ kswz;
  int vbase = (lo >> 1)*64 + ((((lo & 1) << 5) + hi*8) ^ (((lo >> 1) & 7) << 3));

  const u16* kbat = kph + ((size_t)b << 18);
  const u16* vbat = vph + ((size_t)b << 18);

  // stage tile tt into slot: 8 gll16/thread (K 4 + V 4)
  auto STAGE = [&](int tt, int slot){
    const u16* ks = kbat + (size_t)tt * 8192;
    const u16* vs = vbat + (size_t)tt * 8192;
    u16* kd = smem + slot * 8192;
    u16* vd = smem + 24576 + slot * 8192;
    #pragma unroll
    for (int s = 0; s < 4; s++){
      int ch = (s*256 + tid) * 8;
      gll16(ks + ch, kd + ch);
      gll16(vs + ch, vd + ch);
    }
  };

  STAGE(0, 0);
  STAGE(1, 1);
  asm volatile("s_waitcnt vmcnt(8)" ::: "memory");   // retire STAGE(0), keep STAGE(1) in flight
  __builtin_amdgcn_sched_barrier(0);
  __builtin_amdgcn_s_barrier();
  __builtin_amdgcn_sched_barrier(0);

  int slot = 0;
  for (int t = 0; t < 32; t++){
    const u16* Kb = smem + slot*8192;
    const u16* Vb = smem + 24576 + slot*8192;

    // S^T = K · Q
    vfloat4 st[2][2];
    st[0][0] = vfloat4{0.f,0.f,0.f,0.f}; st[0][1] = vfloat4{0.f,0.f,0.f,0.f};
    st[1][0] = vfloat4{0.f,0.f,0.f,0.f}; st[1][1] = vfloat4{0.f,0.f,0.f,0.f};
    __builtin_amdgcn_s_setprio(1);
    #pragma unroll
    for (int ct = 0; ct < 8; ct++){
      vshort8 k0 = *(const vshort8*)(Kb + lo*256 + koff[ct]);
      vshort8 k1 = *(const vshort8*)(Kb + (16 + lo)*256 + koff[ct]);
      st[0][0] = __builtin_amdgcn_mfma_f32_16x16x32_bf16(k0, qf[0][ct], st[0][0], 0,0,0);
      st[0][1] = __builtin_amdgcn_mfma_f32_16x16x32_bf16(k0, qf[1][ct], st[0][1], 0,0,0);
      st[1][0] = __builtin_amdgcn_mfma_f32_16x16x32_bf16(k1, qf[0][ct], st[1][0], 0,0,0);
      st[1][1] = __builtin_amdgcn_mfma_f32_16x16x32_bf16(k1, qf[1][ct], st[1][1], 0,0,0);
    }
    __builtin_amdgcn_s_setprio(0);

    // issue next-next tile staging (depth 2)
    if (t < 30){
      int s2 = slot + 2; if (s2 >= 3) s2 -= 3;
      STAGE(t + 2, s2);
    }

    // online softmax (log2 domain), defer-max THR=8
    float pm[2];
    #pragma unroll
    for (int f = 0; f < 2; f++){
      float a = fmaxf(fmaxf(st[0][f][0], st[0][f][1]), fmaxf(st[0][f][2], st[0][f][3]));
      float c = fmaxf(fmaxf(st[1][f][0], st[1][f][1]), fmaxf(st[1][f][2], st[1][f][3]));
      float p = fmaxf(a, c);
      p = fmaxf(p, __shfl_xor(p, 16));
      p = fmaxf(p, __shfl_xor(p, 32));
      pm[f] = p;
    }
    bool okd = (pm[0] - m_run[0] <= 8.f) && (pm[1] - m_run[1] <= 8.f);
    if (!__all(okd)){
      #pragma unroll
      for (int f = 0; f < 2; f++){
        float mn = fmaxf(m_run[f], pm[f]);
        float corr = exp2f(m_run[f] - mn);
        #pragma unroll
        for (int i = 0; i < 16; i++) Oacc[i][f] *= corr;
        l_run[f] *= corr;
        m_run[f] = mn;
      }
    }
    vshort8 pf[2];
    #pragma unroll
    for (int f = 0; f < 2; f++){
      float p[8], ps = 0.f;
      #pragma unroll
      for (int e = 0; e < 4; e++){
        p[e]   = exp2f(st[0][f][e] - m_run[f]);
        p[4+e] = exp2f(st[1][f][e] - m_run[f]);
        ps += p[e] + p[4+e];
      }
      ps += __shfl_xor(ps, 16); ps += __shfl_xor(ps, 32);
      l_run[f] += ps;
      #pragma unroll
      for (int e2 = 0; e2 < 8; e2++) pf[f][e2] = (short)f2b(p[e2]);
    }

    // PV: O[c][i] += V · P
    __builtin_amdgcn_s_setprio(1);
    #pragma unroll
    for (int ct2 = 0; ct2 < 16; ct2++){
      vshort8 vf = *(const vshort8*)(Vb + ct2*512 + vbase);
      Oacc[ct2][0] = __builtin_amdgcn_mfma_f32_16x16x32_bf16(vf, pf[0], Oacc[ct2][0], 0,0,0);
      Oacc[ct2][1] = __builtin_amdgcn_mfma_f32_16x16x32_bf16(vf, pf[1], Oacc[ct2][1], 0,0,0);
    }
    __builtin_amdgcn_s_setprio(0);

    // counted wait: retire STAGE(t+1) (issued last iter), keep STAGE(t+2) in flight
    if (t < 30){
      asm volatile("s_waitcnt vmcnt(8)" ::: "memory");
    } else {
      asm volatile("s_waitcnt vmcnt(0)" ::: "memory");
    }
    __builtin_amdgcn_sched_barrier(0);
    __builtin_amdgcn_s_barrier();
    __builtin_amdgcn_sched_barrier(0);

    slot++; if (slot == 3) slot = 0;
  }

  float inv[2] = {1.f / l_run[0], 1.f / l_run[1]};
  asm volatile("s_waitcnt vmcnt(0)" ::: "memory");
  __syncthreads();
  u16* Ol = smem;                         // [128 i][264]
  #pragma unroll
  for (int f = 0; f < 2; f++)
    #pragma unroll
    for (int ct2 = 0; ct2 < 16; ct2++){
      vshort4 p;
      #pragma unroll
      for (int r = 0; r < 4; r++) p[r] = (short)f2b(Oacc[ct2][f][r] * inv[f]);
      *(vshort4*)(Ol + (w*32 + f*16 + lo)*264 + ct2*16 + hi*4) = p;
    }
  __syncthreads();

  // proj: wave w -> o in [w*64, w*64+64), all 128 i
  vfloat4 acc2[4][8];
  #pragma unroll
  for (int i = 0; i < 4; i++)
    #pragma unroll
    for (int j = 0; j < 8; j++) acc2[i][j] = vfloat4{0.f,0.f,0.f,0.f};
  #pragma unroll
  for (int ct = 0; ct < 8; ct++){
    vshort8 wf[4], ofr[8];
    #pragma unroll
    for (int o4 = 0; o4 < 4; o4++)
      wf[o4] = *(const vshort8*)(wp_b + (w*64 + o4*16 + lo)*256 + ct*32 + hi*8);
    #pragma unroll
    for (int i4 = 0; i4 < 8; i4++)
      ofr[i4] = *(const vshort8*)(Ol + (i4*16 + lo)*264 + ct*32 + hi*8);
    #pragma unroll
    for (int o4 = 0; o4 < 4; o4++)
      #pragma unroll
      for (int i4 = 0; i4 < 8; i4++)
        acc2[o4][i4] = __builtin_amdgcn_mfma_f32_16x16x32_bf16(wf[o4], ofr[i4], acc2[o4][i4], 0,0,0);
  }

  #pragma unroll
  for (int o4 = 0; o4 < 4; o4++){
    int ob = w*64 + o4*16 + hi*4;
    vfloat4 bp = *(const vfloat4*)(b_proj + ob);
    vfloat4 gt = *(const vfloat4*)(gate + b*256 + ob);
    #pragma unroll
    for (int i4 = 0; i4 < 8; i4++){
      int n = i0 + i4*16 + lo;
      #pragma unroll
      for (int e = 0; e < 4; e++){
        size_t idxo = ((size_t)(b*256) + ob + e)*1024 + n;
        out[idxo] = x[idxo] + (acc2[o4][i4][e] + bp[e]) * gt[e];
      }
    }
  }
}

// ---------------- launch ----------------
extern "C" void kernel_launch(void* const* d_in, const int* in_sizes, int n_in,
                              void* d_out, int out_size, void* d_ws, size_t ws_size,
                              hipStream_t stream){
  const float* x      = (const float*)d_in[0];
  const float* gamma  = (const float*)d_in[1];
  const float* beta   = (const float*)d_in[2];
  const float* w_qkv  = (const float*)d_in[3];
  const float* b_qkv  = (const float*)d_in[4];
  const float* w_proj = (const float*)d_in[5];
  const float* b_proj = (const float*)d_in[6];
  const float* w_se1  = (const float*)d_in[7];
  const float* b_se1  = (const float*)d_in[8];
  const float* w_se2  = (const float*)d_in[9];
  const float* b_se2  = (const float*)d_in[10];
  float* out = (float*)d_out;
  char* ws = (char*)d_ws;

  float* sum  = (float*)(ws + 0);          // 32 KB
  float* sq   = (float*)(ws + 32768);      // 32 KB
  float* a_s  = (float*)(ws + 65536);      // 32 KB
  float* bsh  = (float*)(ws + 98304);      // 32 KB
  float* gate = (float*)(ws + 131072);     // 32 KB
  u16* wq_b   = (u16*)(ws + 163840);       // 384 KB
  u16* wp_b   = (u16*)(ws + 557056);       // 128 KB
  u16* xs_t   = (u16*)(ws + 688128);       // 16 MB  [B,N,C] bf16
  u16* qt     = (u16*)(ws + 17465344);     // 16 MB  [B,N,C] bf16 (scale*log2e folded)
  u16* kph    = (u16*)(ws + 34242560);     // 16 MB  K tile images [B][32][8192]
  u16* vph    = (u16*)(ws + 51019776);     // 16 MB  V tile images [B][32][8192]

  k_stats<<<8192, 256, 0, stream>>>(x, sum, sq);
  k_wcvt <<<1024, 256, 0, stream>>>(w_qkv, w_proj, wq_b, wp_b);
  k_prep <<<32,   256, 0, stream>>>(sum, sq, gamma, beta, w_se1, b_se1, w_se2, b_se2, a_s, bsh, gate);
  k_xt   <<<dim3(16,4,32), 256, 0, stream>>>(x, a_s, bsh, xs_t);
  k_qkv  <<<1536, 256, 0, stream>>>(wq_b, xs_t, b_qkv, qt, kph, vph);
  k_attn <<<256,  256, 0, stream>>>(qt, kph, vph, wp_b, b_proj, gate, x, out);
}

// Round 7
// 119.909 us; speedup vs baseline: 1.9539x; 1.1695x over previous
//
#include <hip/hip_runtime.h>

typedef unsigned short u16;
typedef unsigned int u32;
typedef unsigned long long u64;
typedef __attribute__((ext_vector_type(4))) float vfloat4;
typedef __attribute__((ext_vector_type(16))) float vfloat16;
typedef __attribute__((ext_vector_type(8))) short vshort8;
typedef __attribute__((ext_vector_type(4))) short vshort4;
typedef __attribute__((ext_vector_type(4))) u32 vuint4;

#define DEV __device__ __forceinline__

DEV u16 f2b(float f){
  u32 u = __builtin_bit_cast(u32, f);
  u = (u + 0x7fffu + ((u >> 16) & 1u)) >> 16;
  return (u16)u;
}

typedef __attribute__((address_space(3))) u32 as3u;
typedef __attribute__((address_space(1))) u32 as1u;
DEV void gll16(const u16* g, const u16* l){
  __builtin_amdgcn_global_load_lds((const as1u*)(u64)(uintptr_t)g,
                                   (as3u*)(u32)(u64)(uintptr_t)l, 16, 0, 0);
}

// ---------------- K1: per-(b,c) sum & sumsq over N=1024 ----------------
__global__ void k_stats(const float* __restrict__ x, float* __restrict__ osum, float* __restrict__ osq){
  int row = blockIdx.x;
  const vfloat4* xr = (const vfloat4*)(x + (size_t)row * 1024);
  vfloat4 v = xr[threadIdx.x];
  float s = v[0]+v[1]+v[2]+v[3];
  float q = v[0]*v[0]+v[1]*v[1]+v[2]*v[2]+v[3]*v[3];
  #pragma unroll
  for (int m = 1; m < 64; m <<= 1){ s += __shfl_xor(s, m); q += __shfl_xor(q, m); }
  __shared__ float ls[4], lq[4];
  int w = threadIdx.x >> 6;
  if ((threadIdx.x & 63) == 0){ ls[w] = s; lq[w] = q; }
  __syncthreads();
  if (threadIdx.x == 0){
    osum[row] = ls[0]+ls[1]+ls[2]+ls[3];
    osq[row]  = lq[0]+lq[1]+lq[2]+lq[3];
  }
}

// ---------------- K2: per-batch GN affine + SE gate ----------------
__global__ void k_prep(const float* __restrict__ sum, const float* __restrict__ sq,
                       const float* __restrict__ gamma, const float* __restrict__ beta,
                       const float* __restrict__ w_se1, const float* __restrict__ b_se1,
                       const float* __restrict__ w_se2, const float* __restrict__ b_se2,
                       float* __restrict__ a_scale, float* __restrict__ bsh, float* __restrict__ gate){
  int b = blockIdx.x, c = threadIdx.x;
  __shared__ float ssh[256], qsh[256], pooled[256], h1[64], meang[32], rstdg[32];
  float s = sum[b*256 + c], q = sq[b*256 + c];
  ssh[c] = s; qsh[c] = q; pooled[c] = s * (1.f/1024.f);
  __syncthreads();
  if (c < 32){
    float gs = 0.f, gq = 0.f;
    #pragma unroll
    for (int i = 0; i < 8; i++){ gs += ssh[c*8+i]; gq += qsh[c*8+i]; }
    float mean = gs * (1.f/8192.f);
    float var  = gq * (1.f/8192.f) - mean*mean;
    meang[c] = mean; rstdg[c] = rsqrtf(var + 1e-5f);
  }
  __syncthreads();
  float rs = rstdg[c>>3], mn = meang[c>>3], g = gamma[c];
  a_scale[b*256+c] = rs*g;
  bsh[b*256+c]     = beta[c] - mn*rs*g;
  if (c < 64){
    float acc = b_se1[c];
    const float* wr = w_se1 + c*256;
    for (int i = 0; i < 256; i++) acc += pooled[i]*wr[i];
    h1[c] = fmaxf(acc, 0.f);
  }
  __syncthreads();
  float acc = b_se2[c];
  const float* wr2 = w_se2 + c*64;
  #pragma unroll
  for (int j = 0; j < 64; j++) acc += h1[j]*wr2[j];
  gate[b*256+c] = 1.f / (1.f + __expf(-acc));
}

// ---------------- K3w: weights -> bf16 ----------------
__global__ void k_wcvt(const float* __restrict__ wq, const float* __restrict__ wp,
                       u16* __restrict__ wqb, u16* __restrict__ wpb){
  int i = blockIdx.x*256 + threadIdx.x;
  if (i < 196608) wqb[i] = f2b(wq[i]);
  else            wpb[i-196608] = f2b(wp[i-196608]);
}

// ---------------- K3: xs_t[b,n,c] = bf16(a*x + bsh), transposed ----------------
__global__ void k_xt(const float* __restrict__ x, const float* __restrict__ a_s,
                     const float* __restrict__ bsh, u16* __restrict__ xs_t){
  __shared__ float t[64][65];
  int b = blockIdx.z, c0 = blockIdx.y*64, n0 = blockIdx.x*64;
  int tid = threadIdx.x;
  int rr = tid >> 4, cc = (tid & 15)*4;
  #pragma unroll
  for (int itr = 0; itr < 4; itr++){
    int r = rr + itr*16;
    int c = c0 + r;
    float a = a_s[b*256 + c], bs = bsh[b*256 + c];
    vfloat4 v = *(const vfloat4*)(x + ((size_t)(b*256 + c))*1024 + n0 + cc);
    t[r][cc]   = v[0]*a + bs;
    t[r][cc+1] = v[1]*a + bs;
    t[r][cc+2] = v[2]*a + bs;
    t[r][cc+3] = v[3]*a + bs;
  }
  __syncthreads();
  int cl = tid & 63, rg = tid >> 6;
  #pragma unroll
  for (int it2 = 0; it2 < 16; it2++){
    int nl = rg*16 + it2;
    xs_t[((size_t)b*1024 + n0 + nl)*256 + c0 + cl] = f2b(t[cl][nl]);
  }
}

// ---------------- K4: qkv GEMM; q[b,n,c] (scale*log2e folded),
//   K image: [j][32 16B-slots] slot ^= (j&31)   (conflict-free A-frag reads)
//   V image: 32x32-MFMA A-slot layout, slot ^= (c>>2)&3 (2-way = free) -------
__global__ __launch_bounds__(256) void k_qkv(
    const u16* __restrict__ wq_b, const u16* __restrict__ xs_t,
    const float* __restrict__ b_qkv,
    u16* __restrict__ qt, u16* __restrict__ kph, u16* __restrict__ vph){
  __shared__ u16 Alds[128*40];
  __shared__ u16 Blds[128*40];
  int bid = blockIdx.x;                 // 1536 linear, XCD-aware decode
  int xcd = bid & 7, idx = bid >> 3;
  int b   = xcd*4 + idx/48;
  int rem = idx % 48;
  int o0 = (rem >> 3) * 128;
  int n0 = (rem & 7) * 128;
  int tid = threadIdx.x;
  int w = tid >> 6, lane = tid & 63, lo = lane & 15, hi = lane >> 4;
  int wr = w >> 1, wc = w & 1;
  vfloat4 acc[4][4];
  #pragma unroll
  for (int i = 0; i < 4; i++)
    #pragma unroll
    for (int j = 0; j < 4; j++) acc[i][j] = vfloat4{0.f,0.f,0.f,0.f};

  for (int ks = 0; ks < 8; ks++){
    int c0 = ks*32;
    __syncthreads();
    #pragma unroll
    for (int i = 0; i < 2; i++){
      int cid = tid + i*256;
      int row = cid >> 2, h4 = cid & 3;
      vshort8 a = *(const vshort8*)(wq_b + (o0+row)*256 + c0 + h4*8);
      *(vshort8*)(Alds + row*40 + h4*8) = a;
      vshort8 bl = *(const vshort8*)(xs_t + ((size_t)b*1024 + n0 + row)*256 + c0 + h4*8);
      *(vshort8*)(Blds + row*40 + h4*8) = bl;
    }
    __syncthreads();
    vshort8 af[4], bf[4];
    #pragma unroll
    for (int of = 0; of < 4; of++) af[of] = *(const vshort8*)(Alds + (wr*64+of*16+lo)*40 + hi*8);
    #pragma unroll
    for (int nf = 0; nf < 4; nf++) bf[nf] = *(const vshort8*)(Blds + (wc*64+nf*16+lo)*40 + hi*8);
    #pragma unroll
    for (int of = 0; of < 4; of++)
      #pragma unroll
      for (int nf = 0; nf < 4; nf++)
        acc[of][nf] = __builtin_amdgcn_mfma_f32_16x16x32_bf16(af[of], bf[nf], acc[of][nf], 0, 0, 0);
  }

  int kind = o0 >> 8;                   // 0=q, 1=k, 2=v
  #pragma unroll
  for (int of = 0; of < 4; of++){
    int ob = o0 + wr*64 + of*16 + hi*4;
    vfloat4 bq = *(const vfloat4*)(b_qkv + ob);
    #pragma unroll
    for (int nf = 0; nf < 4; nf++){
      int n = n0 + wc*64 + nf*16 + lo;
      int tile = n >> 5, j = n & 31;
      vfloat4 val = acc[of][nf];
      #pragma unroll
      for (int r = 0; r < 4; r++) val[r] += bq[r];
      if (kind == 0){
        vshort4 p;                      // fold 1/sqrt(C) * log2(e)
        #pragma unroll
        for (int r = 0; r < 4; r++) p[r] = (short)f2b(val[r] * 0.09016844f);
        *(vshort4*)(qt + ((size_t)b*1024 + n)*256 + ob) = p;
      } else if (kind == 1){
        vshort4 p;
        #pragma unroll
        for (int r = 0; r < 4; r++) p[r] = (short)f2b(val[r]);
        int cx = ob - 256;
        int slot = (cx >> 3) ^ j;       // j = j&31 already
        *(vshort4*)(kph + ((size_t)b << 18) + tile*8192 + j*256 + slot*8 + (cx & 7)) = p;
      } else {
        // V: A-slot map for 32x32x16 PV. slot (m,q,e) holds V[c][j],
        // j = (e&3) + 8*(e>>2) + 16m + 4q  (matches P's D-reg residency)
        int m2 = (j >> 4) & 1, q2 = (j >> 2) & 1;
        int e2 = (j & 3) | ((j & 8) >> 1);
        #pragma unroll
        for (int r = 0; r < 4; r++){
          int c = ob - 512 + r;
          int a2 = c >> 2;
          int off = a2*128 + (c & 3)*32 + ((((m2 << 1) | q2) ^ (a2 & 3)) << 3) + e2;
          vph[((size_t)b << 18) + tile*8192 + off] = f2b(val[r]);
        }
      }
    }
  }
}

// ---------------- K5: flash attention + proj + SE gate + residual ----------------
// 256 blocks x 4 waves, 32x32x16 MFMA: wave owns 32 q-rows (i = lane&31).
// In-lane softmax (defer-max, deferred l-sum): zero cross-lane ops common path.
// K+V LDS dbuf via gll16 from pre-swizzled images (R2-proven barrier structure).
__global__ __launch_bounds__(256, 1) void k_attn(
    const u16* __restrict__ qt, const u16* __restrict__ kph, const u16* __restrict__ vph,
    const u16* __restrict__ wp_b, const float* __restrict__ b_proj,
    const float* __restrict__ gate, const float* __restrict__ x,
    float* __restrict__ out){
  __shared__ u16 smem[33792];           // 66KB: K[2][8192] | V[2][8192] at +16384; Ol overlay
  int bid = blockIdx.x;                 // 256 blocks, XCD-pinned
  int xcd = bid & 7, idx = bid >> 3;    // idx 0..31
  int b = xcd*4 + (idx >> 3);
  int i0 = (idx & 7) * 128;
  int tid = threadIdx.x, w = tid >> 6, lane = tid & 63, lo = lane & 15, hi = lane >> 4;
  int jj = lane & 31, q = lane >> 5;    // jj: K-row / V-c-row / q-col i (all lane&31)

  // Q fragments: 16 k-chunks of 16 c (8 bf16 per lane: c = kk*16 + 8q + e)
  int iq = i0 + w*32 + jj;
  vshort8 qf[16];
  #pragma unroll
  for (int kk = 0; kk < 16; kk++)
    qf[kk] = *(const vshort8*)(qt + ((size_t)b*1024 + iq)*256 + kk*16 + q*8);

  vfloat16 Oacc[8];
  #pragma unroll
  for (int ct = 0; ct < 8; ct++)
    #pragma unroll
    for (int e = 0; e < 16; e++) Oacc[ct][e] = 0.f;
  float m_run = -1e30f, l_run = 0.f;

  // lane-constant LDS offsets (u16 units)
  int koff[16];
  #pragma unroll
  for (int kk = 0; kk < 16; kk++)
    koff[kk] = jj*256 + ((((kk << 1) | q) ^ jj) << 3);
  int a0 = jj >> 2;
  int vb = a0*128 + (jj & 3)*32;
  int xm0 = ((q)       ^ (a0 & 3)) << 3;
  int xm1 = ((2 | q)   ^ (a0 & 3)) << 3;

  const u16* kbat = kph + ((size_t)b << 18);
  const u16* vbat = vph + ((size_t)b << 18);

  auto STAGE = [&](int tt, int buf){
    const u16* ks = kbat + (size_t)tt * 8192;
    const u16* vs = vbat + (size_t)tt * 8192;
    u16* kd = smem + buf * 8192;
    u16* vd = smem + 16384 + buf * 8192;
    #pragma unroll
    for (int s = 0; s < 4; s++){
      int ch = (s*256 + tid) * 8;
      gll16(ks + ch, kd + ch);
      gll16(vs + ch, vd + ch);
    }
  };

  STAGE(0, 0);
  __syncthreads();

  for (int t = 0; t < 32; t++){
    int buf = t & 1;
    if (t < 31) STAGE(t + 1, buf ^ 1);
    const u16* Kb = smem + buf*8192;
    const u16* Vb = smem + 16384 + buf*8192;

    // S^T = K · Q : D[j][i], col i = lane&31, rows j = (reg&3)+8*(reg>>2)+4q
    vfloat16 stA, stB;
    #pragma unroll
    for (int e = 0; e < 16; e++){ stA[e] = 0.f; stB[e] = 0.f; }
    __builtin_amdgcn_s_setprio(1);
    #pragma unroll
    for (int kk = 0; kk < 16; kk += 2){
      vshort8 k0 = *(const vshort8*)(Kb + koff[kk]);
      vshort8 k1 = *(const vshort8*)(Kb + koff[kk+1]);
      stA = __builtin_amdgcn_mfma_f32_32x32x16_bf16(k0, qf[kk],   stA, 0,0,0);
      stB = __builtin_amdgcn_mfma_f32_32x32x16_bf16(k1, qf[kk+1], stB, 0,0,0);
    }
    __builtin_amdgcn_s_setprio(0);
    vfloat16 st = stA + stB;

    // in-lane max; defer-max THR=8 (no cross-lane in common path)
    float pml = st[0];
    #pragma unroll
    for (int e = 1; e < 16; e++) pml = fmaxf(pml, st[e]);
    if (!__all(pml - m_run <= 8.f)){
      float po = fmaxf(pml, __shfl_xor(pml, 32));
      float mn = fmaxf(m_run, po);
      float corr = exp2f(m_run - mn);
      #pragma unroll
      for (int ct = 0; ct < 8; ct++) Oacc[ct] *= corr;
      l_run *= corr;
      m_run = mn;
    }

    // P = exp2(st - m); per-lane partial l (cross-lane deferred to end)
    float pv[16]; float ls = 0.f;
    #pragma unroll
    for (int e = 0; e < 16; e++){ pv[e] = exp2f(st[e] - m_run); ls += pv[e]; }
    l_run += ls;

    // pack to bf16 B-frags via v_cvt_pk_bf16_f32 (slot e <-> st-reg 8m+e)
    u32 pw[8];
    #pragma unroll
    for (int rr = 0; rr < 4; rr++){
      asm("v_cvt_pk_bf16_f32 %0, %1, %2" : "=v"(pw[rr])   : "v"(pv[2*rr]),   "v"(pv[2*rr+1]));
      asm("v_cvt_pk_bf16_f32 %0, %1, %2" : "=v"(pw[4+rr]) : "v"(pv[8+2*rr]), "v"(pv[8+2*rr+1]));
    }
    vshort8 pf0 = __builtin_bit_cast(vshort8, vuint4{pw[0], pw[1], pw[2], pw[3]});
    vshort8 pf1 = __builtin_bit_cast(vshort8, vuint4{pw[4], pw[5], pw[6], pw[7]});

    // PV: O[c][i] += V · P  (V A-frags pre-permuted to P's slot map)
    __builtin_amdgcn_s_setprio(1);
    #pragma unroll
    for (int ct = 0; ct < 8; ct++){
      vshort8 v0 = *(const vshort8*)(Vb + ct*1024 + vb + xm0);
      vshort8 v1 = *(const vshort8*)(Vb + ct*1024 + vb + xm1);
      Oacc[ct] = __builtin_amdgcn_mfma_f32_32x32x16_bf16(v0, pf0, Oacc[ct], 0,0,0);
      Oacc[ct] = __builtin_amdgcn_mfma_f32_32x32x16_bf16(v1, pf1, Oacc[ct], 0,0,0);
    }
    __builtin_amdgcn_s_setprio(0);
    __syncthreads();
  }

  // final l: this lane holds half the j's; partner lane (^32) the other half
  float lt = l_run + __shfl_xor(l_run, 32);
  float inv = 1.f / lt;

  __syncthreads();
  u16* Ol = smem;                       // [128 i][264 c] bf16
  #pragma unroll
  for (int ct = 0; ct < 8; ct++)
    #pragma unroll
    for (int qd = 0; qd < 4; qd++){
      vshort4 pk;
      #pragma unroll
      for (int e3 = 0; e3 < 4; e3++) pk[e3] = (short)f2b(Oacc[ct][4*qd + e3] * inv);
      int cb = ct*32 + 8*qd + 4*q;      // D row = c = ct*32 + (r&3)+8*(r>>2)+4q
      *(vshort4*)(Ol + (w*32 + jj)*264 + cb) = pk;
    }
  __syncthreads();

  // proj: wave w -> o in [w*64, w*64+64), all 128 i (16x16 MFMA, unchanged)
  vfloat4 acc2[4][8];
  #pragma unroll
  for (int i = 0; i < 4; i++)
    #pragma unroll
    for (int j = 0; j < 8; j++) acc2[i][j] = vfloat4{0.f,0.f,0.f,0.f};
  #pragma unroll
  for (int ct = 0; ct < 8; ct++){
    vshort8 wf[4], ofr[8];
    #pragma unroll
    for (int o4 = 0; o4 < 4; o4++)
      wf[o4] = *(const vshort8*)(wp_b + (w*64 + o4*16 + lo)*256 + ct*32 + hi*8);
    #pragma unroll
    for (int i4 = 0; i4 < 8; i4++)
      ofr[i4] = *(const vshort8*)(Ol + (i4*16 + lo)*264 + ct*32 + hi*8);
    #pragma unroll
    for (int o4 = 0; o4 < 4; o4++)
      #pragma unroll
      for (int i4 = 0; i4 < 8; i4++)
        acc2[o4][i4] = __builtin_amdgcn_mfma_f32_16x16x32_bf16(wf[o4], ofr[i4], acc2[o4][i4], 0,0,0);
  }

  #pragma unroll
  for (int o4 = 0; o4 < 4; o4++){
    int ob = w*64 + o4*16 + hi*4;
    vfloat4 bp = *(const vfloat4*)(b_proj + ob);
    vfloat4 gt = *(const vfloat4*)(gate + b*256 + ob);
    #pragma unroll
    for (int i4 = 0; i4 < 8; i4++){
      int n = i0 + i4*16 + lo;
      #pragma unroll
      for (int e = 0; e < 4; e++){
        size_t idxo = ((size_t)(b*256) + ob + e)*1024 + n;
        out[idxo] = x[idxo] + (acc2[o4][i4][e] + bp[e]) * gt[e];
      }
    }
  }
}

// ---------------- launch ----------------
extern "C" void kernel_launch(void* const* d_in, const int* in_sizes, int n_in,
                              void* d_out, int out_size, void* d_ws, size_t ws_size,
                              hipStream_t stream){
  const float* x      = (const float*)d_in[0];
  const float* gamma  = (const float*)d_in[1];
  const float* beta   = (const float*)d_in[2];
  const float* w_qkv  = (const float*)d_in[3];
  const float* b_qkv  = (const float*)d_in[4];
  const float* w_proj = (const float*)d_in[5];
  const float* b_proj = (const float*)d_in[6];
  const float* w_se1  = (const float*)d_in[7];
  const float* b_se1  = (const float*)d_in[8];
  const float* w_se2  = (const float*)d_in[9];
  const float* b_se2  = (const float*)d_in[10];
  float* out = (float*)d_out;
  char* ws = (char*)d_ws;

  float* sum  = (float*)(ws + 0);          // 32 KB
  float* sq   = (float*)(ws + 32768);      // 32 KB
  float* a_s  = (float*)(ws + 65536);      // 32 KB
  float* bsh  = (float*)(ws + 98304);      // 32 KB
  float* gate = (float*)(ws + 131072);     // 32 KB
  u16* wq_b   = (u16*)(ws + 163840);       // 384 KB
  u16* wp_b   = (u16*)(ws + 557056);       // 128 KB
  u16* xs_t   = (u16*)(ws + 688128);       // 16 MB  [B,N,C] bf16
  u16* qt     = (u16*)(ws + 17465344);     // 16 MB  [B,N,C] bf16 (scale*log2e folded)
  u16* kph    = (u16*)(ws + 34242560);     // 16 MB  K tile images [B][32][8192]
  u16* vph    = (u16*)(ws + 51019776);     // 16 MB  V tile images [B][32][8192]

  k_stats<<<8192, 256, 0, stream>>>(x, sum, sq);
  k_wcvt <<<1024, 256, 0, stream>>>(w_qkv, w_proj, wq_b, wp_b);
  k_prep <<<32,   256, 0, stream>>>(sum, sq, gamma, beta, w_se1, b_se1, w_se2, b_se2, a_s, bsh, gate);
  k_xt   <<<dim3(16,4,32), 256, 0, stream>>>(x, a_s, bsh, xs_t);
  k_qkv  <<<1536, 256, 0, stream>>>(wq_b, xs_t, b_qkv, qt, kph, vph);
  k_attn <<<256,  256, 0, stream>>>(qt, kph, vph, wp_b, b_proj, gate, x, out);
}